// Round 1
// baseline (198.257 us; speedup 1.0000x reference)
//
#include <hip/hip_runtime.h>

#define NPTS 65536
#define CCH  32
#define DDIM 64
#define GVOX (DDIM*DDIM*DDIM)   // B=1 -> 262144 voxels

typedef _Float16 half8  __attribute__((ext_vector_type(8)));
typedef float    floatx4 __attribute__((ext_vector_type(4)));

// ---------------- prep kernels ----------------

__global__ void k_init(int* __restrict__ map, _Float16* __restrict__ valsh,
                       _Float16* __restrict__ hh) {
  int i = blockIdx.x * blockDim.x + threadIdx.x;
  if (i < GVOX) map[i] = -1;
  if (i < CCH) {                      // zero row at index NPTS (empty-voxel row)
    valsh[NPTS*CCH + i] = (_Float16)0.f;
    hh[NPTS*CCH + i]    = (_Float16)0.f;
  }
}

__global__ void k_points(const int* __restrict__ idx, int* __restrict__ map,
                         int* __restrict__ pcoord) {
  int n = blockIdx.x * blockDim.x + threadIdx.x;
  if (n >= NPTS) return;
  int b = idx[4*n+0], z = idx[4*n+1], y = idx[4*n+2], x = idx[4*n+3];
  int lin = ((b*DDIM + z)*DDIM + y)*DDIM + x;
  map[lin] = n;
  pcoord[n] = (b<<18) | (z<<12) | (y<<6) | x;
}

__global__ void k_cvt(const float* __restrict__ v, _Float16* __restrict__ o, int n) {
  int i = blockIdx.x * blockDim.x + threadIdx.x;
  if (i < n) o[i] = (_Float16)v[i];
}

// transpose (t,cin,cout) f32 -> (t,cout,cin) f16, both weight tensors
__global__ void k_wt(const float* __restrict__ k1, const float* __restrict__ k2,
                     _Float16* __restrict__ w1, _Float16* __restrict__ w2) {
  int i = blockIdx.x * blockDim.x + threadIdx.x;
  if (i >= 27*CCH*CCH) return;
  int t = i / (CCH*CCH), r = i % (CCH*CCH);
  int cin = r / CCH, cout = r % CCH;
  int o = (t*CCH + cout)*CCH + cin;
  w1[o] = (_Float16)k1[i];
  w2[o] = (_Float16)k2[i];
}

// ---------------- main MFMA conv (unclipped sources; boundary pts fixed later) --

// MODE 0: h = relu((conv + mask*bias)*mask) -> f16 out
// MODE 1: out = resid + (conv + mask*bias)*mask -> f32 out
template<int MODE>
__global__ __launch_bounds__(256) void conv_mfma(
    const _Float16* __restrict__ A,        // (NPTS+1) x 32 f16 rows, row NPTS = 0
    const int* __restrict__ map,
    const int* __restrict__ pcoord,
    const _Float16* __restrict__ WT,       // 27 x 32(cout) x 32(cin) f16
    const float* __restrict__ bias,
    const float* __restrict__ mask,
    const float* __restrict__ resid,
    _Float16* __restrict__ hout,
    float* __restrict__ fout)
{
  const int lane = threadIdx.x & 63;
  const int wid  = (blockIdx.x * blockDim.x + threadIdx.x) >> 6;
  const int base = wid * 16;
  const int m    = lane & 15;     // A row / D col index bits
  const int quad = lane >> 4;

  const int p  = base + m;
  const int pc = pcoord[p];
  const int bb = pc >> 18, z = (pc>>12)&63, y = (pc>>6)&63, x = pc&63;
  const int linb = bb << 18;

  floatx4 acc0 = {0.f,0.f,0.f,0.f};
  floatx4 acc1 = {0.f,0.f,0.f,0.f};

#pragma unroll
  for (int t = 0; t < 27; ++t) {
    const int oz = t/9 - 1, oy = (t/3)%3 - 1, ox = t%3 - 1;
    int sz = z - oz, sy = y - oy, sx = x - ox;
    int src;
    if (((sz | sy | sx) & ~63) == 0) {
      src = map[linb | (sz<<12) | (sy<<6) | sx];
      src = (src < 0) ? NPTS : src;        // empty voxel -> zero row
    } else {
      src = NPTS;                          // out of range -> zero row
    }
    half8 a  = *(const half8*)(A  + src*CCH + quad*8);
    half8 b0 = *(const half8*)(WT + (t*CCH +      m)*CCH + quad*8);
    half8 b1 = *(const half8*)(WT + (t*CCH + 16 + m)*CCH + quad*8);
    acc0 = __builtin_amdgcn_mfma_f32_16x16x32_f16(a, b0, acc0, 0, 0, 0);
    acc1 = __builtin_amdgcn_mfma_f32_16x16x32_f16(a, b1, acc1, 0, 0, 0);
  }

  // D layout: col = lane&15, row = quad*4 + reg
  const int col = lane & 15;
  const float bi0 = bias[col], bi1 = bias[col + 16];
#pragma unroll
  for (int reg = 0; reg < 4; ++reg) {
    const int r  = quad*4 + reg;
    const int pr = base + r;
    const float mk = mask[pr];
    float v0 = (acc0[reg] + mk*bi0) * mk;
    float v1 = (acc1[reg] + mk*bi1) * mk;
    if (MODE == 0) {
      v0 = fmaxf(v0, 0.f); v1 = fmaxf(v1, 0.f);
      hout[pr*CCH + col]      = (_Float16)v0;
      hout[pr*CCH + col + 16] = (_Float16)v1;
    } else {
      fout[pr*CCH + col]      = resid[pr*CCH + col]      + v0;
      fout[pr*CCH + col + 16] = resid[pr*CCH + col + 16] + v1;
    }
  }
}

// ---------------- boundary points: full clip-aware recompute ----------------

__device__ __forceinline__ void mkpair(int cc, int j, int& s, int& o) {
  if (cc == 0)           { s = (j == 2) ? 1 : 0;           o = (j == 1) ? 0 : -1; }
  else if (cc == DDIM-1) { s = (j == 0) ? DDIM-2 : DDIM-1; o = (j == 1) ? 0 :  1; }
  else                   { s = cc - 1 + j;                  o = 1 - j; }
}

template<int MODE>
__global__ __launch_bounds__(256) void conv_bnd(
    const _Float16* __restrict__ A,
    const int* __restrict__ map,
    const int* __restrict__ pcoord,
    const _Float16* __restrict__ WT,
    const float* __restrict__ bias,
    const float* __restrict__ mask,
    const float* __restrict__ resid,
    _Float16* __restrict__ hout,
    float* __restrict__ fout)
{
  const int g = threadIdx.x >> 5;        // 8 points per block
  const int c = threadIdx.x & 31;        // cout
  const int p = blockIdx.x * 8 + g;
  if (p >= NPTS) return;
  const int pc = pcoord[p];
  const int bb = pc>>18, z = (pc>>12)&63, y = (pc>>6)&63, x = pc&63;
  const bool bz = (z==0)||(z==DDIM-1), by = (y==0)||(y==DDIM-1), bx = (x==0)||(x==DDIM-1);
  if (!(bz || by || bx)) return;         // interior: MFMA pass already correct
  const int linb = bb << 18;

  float acc = 0.f;
  for (int jz = 0; jz < 3; ++jz) {
    int sz, oz; mkpair(z, jz, sz, oz);
    for (int jy = 0; jy < 3; ++jy) {
      int sy, oy; mkpair(y, jy, sy, oy);
      for (int jx = 0; jx < 3; ++jx) {
        int sx, ox; mkpair(x, jx, sx, ox);
        const int srcm = map[linb | (sz<<12) | (sy<<6) | sx];
        if (srcm < 0) continue;
        const int t = (oz+1)*9 + (oy+1)*3 + (ox+1);
        const _Float16* vr = A  + srcm*CCH;
        const _Float16* wr = WT + (t*CCH + c)*CCH;
        float s = 0.f;
        for (int ci = 0; ci < CCH; ++ci)
          s += (float)vr[ci] * (float)wr[ci];
        acc += s;
      }
    }
  }
  const float mk = mask[p];
  float v = (acc + mk*bias[c]) * mk;
  if (MODE == 0) { v = fmaxf(v, 0.f); hout[p*CCH + c] = (_Float16)v; }
  else           { fout[p*CCH + c] = resid[p*CCH + c] + v; }
}

// ---------------- launch ----------------

extern "C" void kernel_launch(void* const* d_in, const int* in_sizes, int n_in,
                              void* d_out, int out_size, void* d_ws, size_t ws_size,
                              hipStream_t stream) {
  const float* values = (const float*)d_in[0];
  const int*   indices= (const int*)  d_in[1];
  const float* maskv  = (const float*)d_in[2];
  const float* kern1  = (const float*)d_in[3];
  const float* bias1  = (const float*)d_in[4];
  const float* kern2  = (const float*)d_in[5];
  const float* bias2  = (const float*)d_in[6];
  float* out = (float*)d_out;

  char* ws = (char*)d_ws;
  int*      map    = (int*)     (ws + 0);          // 1,048,576 B
  int*      pcoord = (int*)     (ws + 1048576);    //   262,144 B
  _Float16* valsh  = (_Float16*)(ws + 1310720);    // 4,194,368 B  ((N+1)*32)
  _Float16* hh     = (_Float16*)(ws + 5505088);    // 4,194,368 B
  _Float16* wt1    = (_Float16*)(ws + 9699456);    //    55,296 B
  _Float16* wt2    = (_Float16*)(ws + 9754752);    //    55,296 B

  k_init  <<<GVOX/256, 256, 0, stream>>>(map, valsh, hh);
  k_points<<<NPTS/256, 256, 0, stream>>>(indices, map, pcoord);
  k_cvt   <<<(NPTS*CCH)/256, 256, 0, stream>>>(values, valsh, NPTS*CCH);
  k_wt    <<<(27*CCH*CCH + 255)/256, 256, 0, stream>>>(kern1, kern2, wt1, wt2);

  // conv1: values -> h (relu)
  conv_mfma<0><<<NPTS/64, 256, 0, stream>>>(valsh, map, pcoord, wt1, bias1, maskv,
                                            nullptr, hh, nullptr);
  conv_bnd<0> <<<NPTS/8, 256, 0, stream>>>(valsh, map, pcoord, wt1, bias1, maskv,
                                           nullptr, hh, nullptr);
  // conv2: h -> out (+ residual)
  conv_mfma<1><<<NPTS/64, 256, 0, stream>>>(hh, map, pcoord, wt2, bias2, maskv,
                                            values, nullptr, out);
  conv_bnd<1> <<<NPTS/8, 256, 0, stream>>>(hh, map, pcoord, wt2, bias2, maskv,
                                           values, nullptr, out);
}

// Round 2
// 148.519 us; speedup vs baseline: 1.3349x; 1.3349x over previous
//
#include <hip/hip_runtime.h>

#define NPTS 65536
#define CCH  32
#define DDIM 64
#define GVOX (DDIM*DDIM*DDIM)   // B=1 -> 262144 voxels
#define MAXTILES 4128           // >= 65536/16 + 27 (per-class padding)

typedef _Float16 half8  __attribute__((ext_vector_type(8)));
typedef _Float16 half4v __attribute__((ext_vector_type(4)));
typedef float    floatx4 __attribute__((ext_vector_type(4)));

// ---------------- prep0: init + dtype conversion (one launch) ----------------
// ranges: map init | sorted init | values->f16 | weight transpose | zero rows | counters
__global__ __launch_bounds__(256) void k_prep0(
    int* __restrict__ map, int* __restrict__ sorted,
    const float* __restrict__ values, _Float16* __restrict__ valsh,
    const float* __restrict__ k1, const float* __restrict__ k2,
    _Float16* __restrict__ w1, _Float16* __restrict__ w2,
    _Float16* __restrict__ hh, int* __restrict__ pcoord,
    int* __restrict__ cnt, int* __restrict__ slot)
{
  int tid = blockIdx.x * 256 + threadIdx.x;
  if (tid < GVOX/4) { ((int4*)map)[tid] = make_int4(-1,-1,-1,-1); return; }
  tid -= GVOX/4;
  if (tid < MAXTILES*16) { sorted[tid] = NPTS; return; }
  tid -= MAXTILES*16;
  if (tid < (NPTS*CCH)/4) {
    float4 v = ((const float4*)values)[tid];
    half4v h = { (_Float16)v.x, (_Float16)v.y, (_Float16)v.z, (_Float16)v.w };
    ((half4v*)valsh)[tid] = h; return;
  }
  tid -= (NPTS*CCH)/4;
  if (tid < 27*CCH*CCH) {                       // (t,cin,cout) f32 -> (t,cout,cin) f16
    int t = tid/(CCH*CCH), r = tid%(CCH*CCH);
    int cin = r/CCH, cout = r%CCH;
    int o = (t*CCH + cout)*CCH + cin;
    w1[o] = (_Float16)k1[tid]; w2[o] = (_Float16)k2[tid]; return;
  }
  tid -= 27*CCH*CCH;
  if (tid < CCH) { valsh[NPTS*CCH+tid] = (_Float16)0.f; hh[NPTS*CCH+tid] = (_Float16)0.f; return; }
  tid -= CCH;
  if (tid < 27) { cnt[tid] = 0; slot[tid] = 0; return; }
  tid -= 27;
  if (tid == 0) pcoord[NPTS] = 0;               // sentinel point coords
}
#define PREP0_THREADS (GVOX/4 + MAXTILES*16 + (NPTS*CCH)/4 + 27*CCH*CCH + CCH + 27 + 1)

// ---------------- prep1: map + pcoord + class histogram ----------------
__global__ __launch_bounds__(256) void k_prep1(const int* __restrict__ idx,
                                               int* __restrict__ map,
                                               int* __restrict__ pcoord,
                                               int* __restrict__ cls,
                                               int* __restrict__ cnt)
{
  __shared__ int lcnt[27];
  if (threadIdx.x < 27) lcnt[threadIdx.x] = 0;
  __syncthreads();
  const int n = blockIdx.x*256 + threadIdx.x;
  const int b = idx[4*n], z = idx[4*n+1], y = idx[4*n+2], x = idx[4*n+3];
  map[((b*DDIM + z)*DDIM + y)*DDIM + x] = n;
  pcoord[n] = (b<<18) | (z<<12) | (y<<6) | x;
  const int cz = (z==0)?0:((z==DDIM-1)?2:1);
  const int cy = (y==0)?0:((y==DDIM-1)?2:1);
  const int cx = (x==0)?0:((x==DDIM-1)?2:1);
  const int c = cz*9 + cy*3 + cx;
  cls[n] = c;
  atomicAdd(&lcnt[c], 1);
  __syncthreads();
  if (threadIdx.x < 27 && lcnt[threadIdx.x]) atomicAdd(&cnt[threadIdx.x], lcnt[threadIdx.x]);
}

// ---------------- prep2: tiny serial scan over 27 classes ----------------
__global__ void k_prep2(const int* __restrict__ cnt, int* __restrict__ clsbase,
                        int* __restrict__ tstart, int* __restrict__ ntiles)
{
  if (threadIdx.x == 0 && blockIdx.x == 0) {
    int b = 0, tb = 0;
    for (int c = 0; c < 27; ++c) {
      clsbase[c] = b; tstart[c] = tb;
      int nt = (cnt[c] + 15) >> 4;    // tiles for this class (padded to 16)
      b += nt << 4; tb += nt;
    }
    tstart[27] = tb; *ntiles = tb;
  }
}

// ---------------- prep3: scatter into class-sorted order + tile class table --
__global__ __launch_bounds__(256) void k_prep3(const int* __restrict__ cls,
                                               const int* __restrict__ clsbase,
                                               int* __restrict__ slot,
                                               int* __restrict__ sorted,
                                               const int* __restrict__ tstart,
                                               const int* __restrict__ ntp,
                                               int* __restrict__ tileclass)
{
  if (blockIdx.x < NPTS/256) {
    __shared__ int lcnt[27], lbase[27];
    if (threadIdx.x < 27) lcnt[threadIdx.x] = 0;
    __syncthreads();
    const int n = blockIdx.x*256 + threadIdx.x;
    const int c = cls[n];
    const int lrank = atomicAdd(&lcnt[c], 1);
    __syncthreads();
    if (threadIdx.x < 27)
      lbase[threadIdx.x] = lcnt[threadIdx.x] ? atomicAdd(&slot[threadIdx.x], lcnt[threadIdx.x]) : 0;
    __syncthreads();
    sorted[clsbase[c] + lbase[c] + lrank] = n;
  } else {
    const int i = (blockIdx.x - NPTS/256)*256 + threadIdx.x;
    if (i >= MAXTILES) return;
    const int nt = *ntp;
    int c = 13;
    if (i < nt) {
      for (int cc = 0; cc < 27; ++cc)
        if (i >= tstart[cc] && i < tstart[cc+1]) { c = cc; break; }
    }
    tileclass[i] = c;
  }
}

// ---------------- unified gather-MFMA conv (handles clipping via class) -------
// Per clipped dim c=0:  j -> (src, tap) = (0,-1),(0,0),(1,-1); c=63: (62,+1),(63,0),(63,+1)
// expressed as src = clamp(c-1+j), tapidx = ot(class,j). All 16 points in a tile
// share a class so tapidx is wave-uniform -> one B fragment per tap.
template<int MODE>
__global__ __launch_bounds__(256) void conv_mfma(
    const _Float16* __restrict__ A,        // (NPTS+1) x 32 f16, row NPTS = zeros
    const int* __restrict__ map,
    const int* __restrict__ pcoord,
    const int* __restrict__ sorted,
    const int* __restrict__ tileclass,
    const int* __restrict__ ntp,
    const _Float16* __restrict__ WT,       // 27 x cout x cin f16
    const float* __restrict__ bias,
    const float* __restrict__ mask,
    const float* __restrict__ resid,
    _Float16* __restrict__ hout,
    float* __restrict__ fout)
{
  const int tile = blockIdx.x*4 + (threadIdx.x >> 6);
  if (tile >= *ntp) return;
  const int lane = threadIdx.x & 63;
  const int m = lane & 15, quad = lane >> 4;
  const int scls = __builtin_amdgcn_readfirstlane(tileclass[tile]);
  const int cz = scls/9, cy = (scls/3)%3, cx = scls%3;

  const int pid = sorted[tile*16 + m];
  const int pc  = pcoord[pid];
  const int bb = pc>>18, z = (pc>>12)&63, y = (pc>>6)&63, x = pc&63;
  const int linb = bb << 18;
  const int az[3] = { max(z-1,0)<<12, z<<12, min(z+1,DDIM-1)<<12 };
  const int ay[3] = { max(y-1,0)<<6,  y<<6,  min(y+1,DDIM-1)<<6 };
  const int ax[3] = { max(x-1,0),     x,     min(x+1,DDIM-1) };

  floatx4 acc0 = {0.f,0.f,0.f,0.f};
  floatx4 acc1 = {0.f,0.f,0.f,0.f};

#pragma unroll
  for (int j = 0; j < 27; ++j) {
    const int jz = j/9, jy = (j/3)%3, jx = j%3;
    // per-dim tap index given class (scalar: jz/jy/jx are compile-time)
    const int tz = (cz==1) ? (2-jz) : ((jz==1) ? 1 : ((cz==0) ? 0 : 2));
    const int ty = (cy==1) ? (2-jy) : ((jy==1) ? 1 : ((cy==0) ? 0 : 2));
    const int tx = (cx==1) ? (2-jx) : ((jx==1) ? 1 : ((cx==0) ? 0 : 2));
    const int t  = tz*9 + ty*3 + tx;
    int src = map[linb | az[jz] | ay[jy] | ax[jx]];
    src = (src < 0) ? NPTS : src;          // empty voxel -> zero row
    half8 a  = *(const half8*)(A + src*CCH + quad*8);
    const _Float16* wr = WT + t*(CCH*CCH);
    half8 b0 = *(const half8*)(wr + m*CCH + quad*8);
    half8 b1 = *(const half8*)(wr + (16+m)*CCH + quad*8);
    acc0 = __builtin_amdgcn_mfma_f32_16x16x32_f16(a, b0, acc0, 0, 0, 0);
    acc1 = __builtin_amdgcn_mfma_f32_16x16x32_f16(a, b1, acc1, 0, 0, 0);
  }

  // D layout: col(N=cout) = lane&15, row(M=point) = quad*4 + reg
  const float bi0 = bias[m], bi1 = bias[m+16];
#pragma unroll
  for (int reg = 0; reg < 4; ++reg) {
    const int r  = quad*4 + reg;
    const int pr = sorted[tile*16 + r];
    if (pr >= NPTS) continue;              // padded lane
    const float mk = mask[pr];
    float v0 = (acc0[reg] + mk*bi0) * mk;
    float v1 = (acc1[reg] + mk*bi1) * mk;
    if (MODE == 0) {
      v0 = fmaxf(v0, 0.f); v1 = fmaxf(v1, 0.f);
      hout[pr*CCH + m]      = (_Float16)v0;
      hout[pr*CCH + m + 16] = (_Float16)v1;
    } else {
      fout[pr*CCH + m]      = resid[pr*CCH + m]      + v0;
      fout[pr*CCH + m + 16] = resid[pr*CCH + m + 16] + v1;
    }
  }
}

// ---------------- launch ----------------

extern "C" void kernel_launch(void* const* d_in, const int* in_sizes, int n_in,
                              void* d_out, int out_size, void* d_ws, size_t ws_size,
                              hipStream_t stream) {
  const float* values = (const float*)d_in[0];
  const int*   indices= (const int*)  d_in[1];
  const float* maskv  = (const float*)d_in[2];
  const float* kern1  = (const float*)d_in[3];
  const float* bias1  = (const float*)d_in[4];
  const float* kern2  = (const float*)d_in[5];
  const float* bias2  = (const float*)d_in[6];
  float* out = (float*)d_out;

  char* ws = (char*)d_ws;
  size_t off = 0;
  auto alloc = [&](size_t bytes) { void* p = ws + off; off = (off + bytes + 255) & ~(size_t)255; return p; };
  int*      map      = (int*)     alloc(GVOX*4);            // 1 MB
  int*      pcoord   = (int*)     alloc((NPTS+1)*4);
  int*      cls      = (int*)     alloc(NPTS*4);
  int*      sorted   = (int*)     alloc(MAXTILES*16*4);
  int*      tileclass= (int*)     alloc(MAXTILES*4);
  int*      cnt      = (int*)     alloc(27*4);
  int*      slot     = (int*)     alloc(27*4);
  int*      clsbase  = (int*)     alloc(27*4);
  int*      tstart   = (int*)     alloc(28*4);
  int*      ntiles   = (int*)     alloc(4);
  _Float16* valsh    = (_Float16*)alloc((NPTS+1)*CCH*2);    // 4 MB
  _Float16* hh       = (_Float16*)alloc((NPTS+1)*CCH*2);    // 4 MB
  _Float16* wt1      = (_Float16*)alloc(27*CCH*CCH*2);
  _Float16* wt2      = (_Float16*)alloc(27*CCH*CCH*2);

  k_prep0<<<(PREP0_THREADS + 255)/256, 256, 0, stream>>>(
      map, sorted, values, valsh, kern1, kern2, wt1, wt2, hh, pcoord, cnt, slot);
  k_prep1<<<NPTS/256, 256, 0, stream>>>(indices, map, pcoord, cls, cnt);
  k_prep2<<<1, 64, 0, stream>>>(cnt, clsbase, tstart, ntiles);
  k_prep3<<<NPTS/256 + (MAXTILES+255)/256, 256, 0, stream>>>(
      cls, clsbase, slot, sorted, tstart, ntiles, tileclass);

  conv_mfma<0><<<MAXTILES/4, 256, 0, stream>>>(valsh, map, pcoord, sorted, tileclass,
                                               ntiles, wt1, bias1, maskv, nullptr, hh, nullptr);
  conv_mfma<1><<<MAXTILES/4, 256, 0, stream>>>(hh, map, pcoord, sorted, tileclass,
                                               ntiles, wt2, bias2, maskv, values, nullptr, out);
}